// Round 1
// baseline (751.628 us; speedup 1.0000x reference)
//
#include <hip/hip_runtime.h>

// Problem constants
#define BB   512
#define CC   22
#define TT   1000
#define HH   64
#define G4   256   // 4*H
#define NCLS 4
#define TC   250   // time chunk staged in LDS
#define NCHUNK (TT / TC)
#define XPAD 24    // padded channels per timestep in LDS (16B-multiple rows)

__device__ __forceinline__ float sigmoidf_fast(float x) {
    return 1.0f / (1.0f + __expf(-x));   // x->-inf: 1/(1+inf)=0, no NaN
}
__device__ __forceinline__ float tanhf_fast(float x) {
    float e = __expf(-2.0f * fabsf(x));  // in (0,1], no overflow
    float r = (1.0f - e) / (1.0f + e);
    return copysignf(r, x);
}

// One block per batch row. Thread j (0..255) owns gate j = wave*64+lane
// (wave = gate type i/f/g/o -> wave-uniform activation branch).
// W_hh row + W_ih row held in registers. h replicated per-wave in LDS so the
// h-publish is intra-wave only; ONE barrier per timestep (gate publish),
// gate buffer double-buffered to remove the WAR race.
__global__ __launch_bounds__(256, 2) void lstm_net_kernel(
    const float* __restrict__ x,     // [B, C, T]
    const float* __restrict__ W_ih,  // [4H, C]
    const float* __restrict__ W_hh,  // [4H, H]
    const float* __restrict__ b_ih,  // [4H]
    const float* __restrict__ b_hh,  // [4H]
    const float* __restrict__ W_fc,  // [NCLS, T*H]
    const float* __restrict__ b_fc,  // [NCLS]
    float* __restrict__ out)         // [B, NCLS]
{
    __shared__ float xs[TC * XPAD];      // 24000 B, x chunk transposed [t][c]
    __shared__ float gate[2][G4];        // 2048 B, double-buffered gates
    __shared__ float hbuf[4][HH];        // 1024 B, per-wave h copy
    __shared__ float logit[NCLS];

    const int j    = threadIdx.x;
    const int b    = blockIdx.x;
    const int wave = j >> 6;
    const int lane = j & 63;

    // ---- load per-thread weights into registers (one-time) ----
    float whh[HH];
    {
        const float4* wq = (const float4*)(W_hh + j * HH);  // 256B-aligned rows
        #pragma unroll
        for (int k = 0; k < HH / 4; ++k) {
            float4 v = wq[k];
            whh[4*k+0] = v.x; whh[4*k+1] = v.y; whh[4*k+2] = v.z; whh[4*k+3] = v.w;
        }
    }
    float wih[CC];
    {
        const float2* w2 = (const float2*)(W_ih + j * CC);  // 8B-aligned rows
        #pragma unroll
        for (int k = 0; k < CC / 2; ++k) {
            float2 v = w2[k];
            wih[2*k+0] = v.x; wih[2*k+1] = v.y;
        }
    }
    const float bias = b_ih[j] + b_hh[j];

    hbuf[wave][lane] = 0.0f;     // own-wave copy; intra-wave ordering suffices
    float c_reg  = 0.0f;         // cell state for `lane`, replicated per wave
    float fc_acc = 0.0f;         // FC partial: sum_t h[t][lane]*W_fc[wave][t*64+lane]
    const float* wfc_ptr = W_fc + wave * (TT * HH) + lane;

    const float* xrow = x + (size_t)b * (CC * TT);
    int p = 0;

    for (int chunk = 0; chunk < NCHUNK; ++chunk) {
        __syncthreads();  // previous chunk's xs reads are done
        // stage x chunk, transposed: xs[t][c]; global reads coalesced along t
        for (int idx = j; idx < CC * TC; idx += 256) {
            int c  = idx / TC;
            int t0 = idx - c * TC;
            xs[t0 * XPAD + c] = xrow[c * TT + chunk * TC + t0];
        }
        __syncthreads();

        for (int tt = 0; tt < TC; ++tt) {
            // FC weight for this step (L2-resident, issued early to hide latency)
            float wfcv = *wfc_ptr;
            wfc_ptr += HH;

            // input projection: broadcast LDS reads, weights in registers
            const float4* xq = (const float4*)&xs[tt * XPAD];
            float xacc = bias;
            #pragma unroll
            for (int q = 0; q < 5; ++q) {
                float4 v = xq[q];
                xacc += v.x * wih[4*q+0] + v.y * wih[4*q+1]
                      + v.z * wih[4*q+2] + v.w * wih[4*q+3];
            }
            {
                float2 v = *(const float2*)&xs[tt * XPAD + 20];
                xacc += v.x * wih[20] + v.y * wih[21];
            }

            // recurrent dot: h (own-wave LDS copy, broadcast reads) x W_hh row (regs)
            const float4* hq = (const float4*)&hbuf[wave][0];
            float a0 = 0.f, a1 = 0.f, a2 = 0.f, a3 = 0.f;
            #pragma unroll
            for (int k = 0; k < HH / 4; ++k) {
                float4 h = hq[k];
                a0 += h.x * whh[4*k+0];
                a1 += h.y * whh[4*k+1];
                a2 += h.z * whh[4*k+2];
                a3 += h.w * whh[4*k+3];
            }
            float g = xacc + ((a0 + a1) + (a2 + a3));

            // wave-uniform activation; publish gate
            float act = (wave == 2) ? tanhf_fast(g) : sigmoidf_fast(g);
            gate[p][j] = act;
            __syncthreads();   // the ONE per-step barrier

            // every thread redundantly updates (c,h) for its lane
            float iv = gate[p][lane];
            float fv = gate[p][64  + lane];
            float gv = gate[p][128 + lane];
            float ov = gate[p][192 + lane];
            c_reg = fv * c_reg + iv * gv;
            float hv = ov * tanhf_fast(c_reg);
            hbuf[wave][lane] = hv;          // own-wave publish, no barrier needed
            fc_acc += hv * wfcv;
            p ^= 1;
        }
    }

    // ---- FC reduce (64 lanes -> logit[wave]) + softmax ----
    #pragma unroll
    for (int off = 32; off > 0; off >>= 1)
        fc_acc += __shfl_down(fc_acc, off);
    if (lane == 0) logit[wave] = fc_acc + b_fc[wave];
    __syncthreads();
    if (j < NCLS) {
        float l0 = logit[0], l1 = logit[1], l2 = logit[2], l3 = logit[3];
        float m  = fmaxf(fmaxf(l0, l1), fmaxf(l2, l3));
        float e0 = __expf(l0 - m), e1 = __expf(l1 - m);
        float e2 = __expf(l2 - m), e3 = __expf(l3 - m);
        float s  = e0 + e1 + e2 + e3;
        float mine = (j == 0) ? e0 : (j == 1) ? e1 : (j == 2) ? e2 : e3;
        out[b * NCLS + j] = mine / s;
    }
}

extern "C" void kernel_launch(void* const* d_in, const int* in_sizes, int n_in,
                              void* d_out, int out_size, void* d_ws, size_t ws_size,
                              hipStream_t stream) {
    const float* x    = (const float*)d_in[0];
    const float* W_ih = (const float*)d_in[1];
    const float* W_hh = (const float*)d_in[2];
    const float* b_ih = (const float*)d_in[3];
    const float* b_hh = (const float*)d_in[4];
    const float* W_fc = (const float*)d_in[5];
    const float* b_fc = (const float*)d_in[6];
    float* out = (float*)d_out;

    lstm_net_kernel<<<BB, 256, 0, stream>>>(x, W_ih, W_hh, b_ih, b_hh, W_fc, b_fc, out);
}